// Round 1
// baseline (287.349 us; speedup 1.0000x reference)
//
#include <hip/hip_runtime.h>

// LightCoordAtt: x (N,C,H,W) f32 in, f32 out. N=16, C=256, H=W=80, mip=8, L=160.
// Dtypes settled in prior session: f32 in, f32 out (bf16 paths failed absmax).
//
// R4 structure (3 dispatches, mid kernel folded away):
//   zero : y_acc (80 KB) = 0                                        [~2 us]
//   pool : per-(n, c-pair) -> LDS -> row/col means for 2 planes ->
//          per-l register combine of both channels' w_fc products ->
//          atomicAdd into y_acc[n,l,m]   (2.6M f32 atomics, 20K addrs)
//   apply: BN+swish+gate prologue from y_acc (L2-hot), then
//          out = x * ah * aw float4 stream
// Grid-wide dep (y needs all c) crossed at the pool->apply boundary only.
#define N_   16
#define C_   256
#define H_   80
#define W_   80
#define MIP_ 8
#define L_   160

// ---------------------------------------------------------------------------
// Kernel 0: zero the accumulator. 80 blocks x 256 = 20480 = N*L*MIP exactly.
// ---------------------------------------------------------------------------
__global__ __launch_bounds__(256) void zero_kernel(float* __restrict__ y_acc) {
    y_acc[blockIdx.x * 256 + threadIdx.x] = 0.0f;
}

// ---------------------------------------------------------------------------
// Kernel 1: pooled means for TWO channel planes + w_fc partial products,
// accumulated grid-wide via atomicAdd. Block b: n = b/128, c0 = 2*(b%128).
// Plane-1 global loads are issued into registers BEFORE plane-0's reduction
// so their ~500cy HBM latency hides under the LDS reads.
// ---------------------------------------------------------------------------
__global__ __launch_bounds__(256) void pool_mid_kernel(const float* __restrict__ x,
                                                       const float* __restrict__ w_fc,
                                                       float* __restrict__ y_acc) {
    __shared__ float lds[H_ * 81];      // stride 81: conflict-free col reads
    __shared__ float pool[2][L_];       // [plane][l]: l<80 row means, l>=80 col means
    const int b  = blockIdx.x;
    const int n  = b >> 7;              // b / 128
    const int c0 = (b & 127) << 1;      // 2 * (b % 128)
    const int t  = threadIdx.x;

    const float4* pv0 = reinterpret_cast<const float4*>(x + (size_t)(n * C_ + c0)     * (H_ * W_));
    const float4* pv1 = reinterpret_cast<const float4*>(x + (size_t)(n * C_ + c0 + 1) * (H_ * W_));

    // ---- plane 0: global -> LDS (7 float4 in flight per thread) ----
    #pragma unroll
    for (int it = 0; it < 7; ++it) {
        int v = t + it * 256;
        if (v < 1600) {
            float4 q = pv0[v];
            int row  = v / 20;
            int col0 = (v - row * 20) * 4;
            float* dst = &lds[row * 81 + col0];
            dst[0] = q.x; dst[1] = q.y; dst[2] = q.z; dst[3] = q.w;
        }
    }
    __syncthreads();

    // ---- issue plane-1 loads into registers (overlaps reduce below) ----
    float4 qb[7];
    #pragma unroll
    for (int it = 0; it < 7; ++it) {
        int v = t + it * 256;
        if (v < 1600) qb[it] = pv1[v];
    }

    // ---- plane 0 reduce ----
    if (t < H_) {                              // waves 0-1: row means (x_h)
        float s0 = 0.f, s1 = 0.f, s2 = 0.f, s3 = 0.f;
        const float* r = &lds[t * 81];
        #pragma unroll
        for (int c4 = 0; c4 < W_; c4 += 4) {
            s0 += r[c4]; s1 += r[c4 + 1]; s2 += r[c4 + 2]; s3 += r[c4 + 3];
        }
        pool[0][t] = (s0 + s1 + s2 + s3) * (1.0f / (float)W_);
    } else if (t >= 128 && t < 128 + W_) {     // waves 2-3: col means (x_w)
        const int j = t - 128;
        float s0 = 0.f, s1 = 0.f, s2 = 0.f, s3 = 0.f;
        #pragma unroll
        for (int r4 = 0; r4 < H_; r4 += 4) {
            s0 += lds[(r4    ) * 81 + j];
            s1 += lds[(r4 + 1) * 81 + j];
            s2 += lds[(r4 + 2) * 81 + j];
            s3 += lds[(r4 + 3) * 81 + j];
        }
        pool[0][H_ + j] = (s0 + s1 + s2 + s3) * (1.0f / (float)H_);
    }
    __syncthreads();                            // plane-0 LDS reads done

    // ---- plane 1: registers -> LDS ----
    #pragma unroll
    for (int it = 0; it < 7; ++it) {
        int v = t + it * 256;
        if (v < 1600) {
            int row  = v / 20;
            int col0 = (v - row * 20) * 4;
            float* dst = &lds[row * 81 + col0];
            dst[0] = qb[it].x; dst[1] = qb[it].y; dst[2] = qb[it].z; dst[3] = qb[it].w;
        }
    }
    __syncthreads();

    // ---- plane 1 reduce ----
    if (t < H_) {
        float s0 = 0.f, s1 = 0.f, s2 = 0.f, s3 = 0.f;
        const float* r = &lds[t * 81];
        #pragma unroll
        for (int c4 = 0; c4 < W_; c4 += 4) {
            s0 += r[c4]; s1 += r[c4 + 1]; s2 += r[c4 + 2]; s3 += r[c4 + 3];
        }
        pool[1][t] = (s0 + s1 + s2 + s3) * (1.0f / (float)W_);
    } else if (t >= 128 && t < 128 + W_) {
        const int j = t - 128;
        float s0 = 0.f, s1 = 0.f, s2 = 0.f, s3 = 0.f;
        #pragma unroll
        for (int r4 = 0; r4 < H_; r4 += 4) {
            s0 += lds[(r4    ) * 81 + j];
            s1 += lds[(r4 + 1) * 81 + j];
            s2 += lds[(r4 + 2) * 81 + j];
            s3 += lds[(r4 + 3) * 81 + j];
        }
        pool[1][H_ + j] = (s0 + s1 + s2 + s3) * (1.0f / (float)H_);
    }
    __syncthreads();

    // ---- combine both channels' mid-GEMM contribution, one atomic stream ----
    if (t < L_) {
        const float p0 = pool[0][t];
        const float p1 = pool[1][t];
        float* dst = y_acc + ((size_t)n * L_ + t) * MIP_;   // 32B/thread, coalesced
        #pragma unroll
        for (int m = 0; m < MIP_; ++m) {
            // w_fc reads are block-uniform -> scalarized by compiler
            float contrib = p0 * w_fc[m * C_ + c0] + p1 * w_fc[m * C_ + c0 + 1];
            atomicAdd(dst + m, contrib);
        }
    }
}

// ---------------------------------------------------------------------------
// Kernel 2: BN + swish + gates from raw y_acc (80 KB, L2-hot), then
//           out[n,c,h,w] = x * sigmoid(w_h[c].y_h[h]) * sigmoid(w_w[c].y_w[w])
// ---------------------------------------------------------------------------
__global__ __launch_bounds__(256) void apply_kernel(const float* __restrict__ x,
                                                    const float* __restrict__ y_acc,
                                                    const float* __restrict__ g,
                                                    const float* __restrict__ be,
                                                    const float* __restrict__ mu,
                                                    const float* __restrict__ va,
                                                    const float* __restrict__ w_h,
                                                    const float* __restrict__ w_w,
                                                    float* __restrict__ out) {
    __shared__ float lah[H_];
    __shared__ float law[W_];
    const int b = blockIdx.x;             // n*C_ + c
    const int n = b >> 8;
    const int c = b & 255;
    const int t = threadIdx.x;

    if (t < L_) {
        const float4* yp = reinterpret_cast<const float4*>(y_acc + ((size_t)n * L_ + t) * MIP_);
        float4 a0 = yp[0], a1 = yp[1];    // coalesced 32B/thread, L2-hot
        float acc[MIP_] = {a0.x, a0.y, a0.z, a0.w, a1.x, a1.y, a1.z, a1.w};
        const float* wp = ((t < H_) ? w_h : w_w) + c * MIP_;
        float s = 0.f;
        #pragma unroll
        for (int m = 0; m < MIP_; ++m) {
            float inv = g[m] * rsqrtf(va[m] + 1e-5f);        // uniform -> scalar
            float yv  = acc[m] * inv + (be[m] - mu[m] * inv);
            float sw  = yv / (1.0f + expf(-yv));             // swish
            s += sw * wp[m];
        }
        float gate = 1.0f / (1.0f + expf(-s));
        if (t < H_) lah[t] = gate; else law[t - H_] = gate;
    }
    __syncthreads();

    const float4* xv = reinterpret_cast<const float4*>(x + (size_t)b * (H_ * W_));
    float4*       ov = reinterpret_cast<float4*>(out + (size_t)b * (H_ * W_));
    #pragma unroll
    for (int it = 0; it < 7; ++it) {
        int v = t + it * 256;
        if (v < 1600) {
            float4 q = xv[v];
            int row  = v / 20;
            int col0 = (v - row * 20) * 4;
            const float ah = lah[row];
            float4 o;
            o.x = q.x * ah * law[col0    ];
            o.y = q.y * ah * law[col0 + 1];
            o.z = q.z * ah * law[col0 + 2];
            o.w = q.w * ah * law[col0 + 3];
            ov[v] = o;
        }
    }
}

extern "C" void kernel_launch(void* const* d_in, const int* in_sizes, int n_in,
                              void* d_out, int out_size, void* d_ws, size_t ws_size,
                              hipStream_t stream) {
    const float* x    = (const float*)d_in[0];
    const float* w_fc = (const float*)d_in[1];
    const float* g    = (const float*)d_in[2];
    const float* be   = (const float*)d_in[3];
    const float* mu   = (const float*)d_in[4];
    const float* va   = (const float*)d_in[5];
    const float* w_h  = (const float*)d_in[6];
    const float* w_w  = (const float*)d_in[7];
    float* out   = (float*)d_out;
    float* y_acc = (float*)d_ws;                         // N*L*MIP floats = 80 KB

    zero_kernel    <<<(N_ * L_ * MIP_) / 256, 256, 0, stream>>>(y_acc);
    pool_mid_kernel<<<N_ * C_ / 2,            256, 0, stream>>>(x, w_fc, y_acc);
    apply_kernel   <<<N_ * C_,                256, 0, stream>>>(x, y_acc, g, be, mu, va, w_h, w_w, out);
}

// Round 3
// 223.292 us; speedup vs baseline: 1.2869x; 1.2869x over previous
//
#include <hip/hip_runtime.h>

// LightCoordAtt: x (N,C,H,W) f32 in, f32 out. N=16, C=256, H=W=80, mip=8, L=160.
// Dtypes settled in prior session: f32 in, f32 out (bf16 paths failed absmax).
//
// R3 = R0 3-kernel structure (225 us) + non-temporal stores in apply.
// R1 lesson: no fine-grained cross-XCD atomics to small shared buffers
// (2.6M atomicAdds onto 20K addrs -> 84 MB HBM write-back, 116 us dispatch).
// R2 lesson: __builtin_nontemporal_store needs a NATIVE clang vector type,
// not HIP's float4 class -> use ext_vector_type(4) float for the store.
//
// Structure (3 launches; grid-wide dep: every gate depends on all C channels):
//   pool : per-(n,c) plane -> LDS -> row means + col means -> pooled (n,c,l)
//   mid  : per-(n,l) -> y[m] = BN+swish( w_fc . pooled[n,:,l] ) -> y (n,l,8)
//   apply: per-(n,c) -> gates from y + w_h/w_w inline, out = x*ah*aw
//          out written with nontemporal float4 stores: out is write-once,
//          never re-read; keep x L3-resident instead of letting out evict it.
#define N_   16
#define C_   256
#define H_   80
#define W_   80
#define MIP_ 8
#define L_   160

typedef float f32x4 __attribute__((ext_vector_type(4)));   // native vector for NT store

// ---------------------------------------------------------------------------
// Kernel 1: per-(n,c) plane H-mean and W-mean. pooled layout: (n, c, l).
// ---------------------------------------------------------------------------
__global__ __launch_bounds__(256) void pool_kernel(const float* __restrict__ x,
                                                   float* __restrict__ pooled) {
    __shared__ float lds[H_ * 81];   // stride 81: odd stride -> conflict-free col reads
    const int b = blockIdx.x;        // n*C_ + c
    const int t = threadIdx.x;

    const float4* pv = reinterpret_cast<const float4*>(x + (size_t)b * (H_ * W_));
    #pragma unroll
    for (int it = 0; it < 7; ++it) {          // 1600 float4, 20 per row
        int v = t + it * 256;
        if (v < 1600) {
            float4 q = pv[v];
            int row  = v / 20;
            int col0 = (v - row * 20) * 4;
            float* dst = &lds[row * 81 + col0];
            dst[0] = q.x; dst[1] = q.y; dst[2] = q.z; dst[3] = q.w;
        }
    }
    __syncthreads();

    float* outp = pooled + (size_t)b * L_;
    if (t < H_) {                              // waves 0-1: row means -> x_h
        float s0 = 0.f, s1 = 0.f, s2 = 0.f, s3 = 0.f;
        const float* r = &lds[t * 81];
        #pragma unroll
        for (int c4 = 0; c4 < W_; c4 += 4) {
            s0 += r[c4]; s1 += r[c4 + 1]; s2 += r[c4 + 2]; s3 += r[c4 + 3];
        }
        outp[t] = (s0 + s1 + s2 + s3) * (1.0f / (float)W_);
    } else if (t >= 128 && t < 128 + W_) {     // waves 2-3: col means -> x_w
        const int j = t - 128;
        float s0 = 0.f, s1 = 0.f, s2 = 0.f, s3 = 0.f;
        #pragma unroll
        for (int r4 = 0; r4 < H_; r4 += 4) {
            s0 += lds[(r4    ) * 81 + j];
            s1 += lds[(r4 + 1) * 81 + j];
            s2 += lds[(r4 + 2) * 81 + j];
            s3 += lds[(r4 + 3) * 81 + j];
        }
        outp[H_ + j] = (s0 + s1 + s2 + s3) * (1.0f / (float)H_);
    }
}

// ---------------------------------------------------------------------------
// Kernel 2: y[n,l,m] = swish( BN( sum_c w_fc[m,c] * pooled[n,c,l] ) )
// ---------------------------------------------------------------------------
__global__ __launch_bounds__(256) void mid_kernel(const float* __restrict__ pooled,
                                                  const float* __restrict__ w_fc,
                                                  const float* __restrict__ g,
                                                  const float* __restrict__ be,
                                                  const float* __restrict__ mu,
                                                  const float* __restrict__ va,
                                                  float* __restrict__ y_out) {
    __shared__ float red[4 * MIP_];
    const int b    = blockIdx.x;          // n*L_ + l
    const int n    = b / L_;
    const int l    = b - n * L_;
    const int c    = threadIdx.x;
    const int lane = c & 63;
    const int wid  = c >> 6;

    // scattered 4B reads at 640B stride; pooled is 2.6 MB, L2/L3-hot
    const float p = pooled[((size_t)n * C_ + c) * L_ + l];

    #pragma unroll
    for (int m = 0; m < MIP_; ++m) {
        float v = w_fc[m * C_ + c] * p;
        #pragma unroll
        for (int off = 32; off > 0; off >>= 1) v += __shfl_down(v, off, 64);
        if (lane == 0) red[wid * MIP_ + m] = v;
    }
    __syncthreads();

    if (c < MIP_) {
        float y   = red[c] + red[MIP_ + c] + red[2 * MIP_ + c] + red[3 * MIP_ + c];
        float inv = g[c] * rsqrtf(va[c] + 1e-5f);
        y = y * inv + (be[c] - mu[c] * inv);
        y_out[(size_t)b * MIP_ + c] = y / (1.0f + expf(-y));   // swish
    }
}

// ---------------------------------------------------------------------------
// Kernel 3: gates inline, then out[n,c,h,w] = x * sigmoid(w_h[c].y_h[h]) *
//                                                 sigmoid(w_w[c].y_w[w])
// ---------------------------------------------------------------------------
__global__ __launch_bounds__(256) void apply_kernel(const float* __restrict__ x,
                                                    const float* __restrict__ y,
                                                    const float* __restrict__ w_h,
                                                    const float* __restrict__ w_w,
                                                    float* __restrict__ out) {
    __shared__ float lah[H_];
    __shared__ float law[W_];
    const int b = blockIdx.x;             // n*C_ + c
    const int n = b >> 8;
    const int c = b & 255;
    const int t = threadIdx.x;

    if (t < L_) {
        const float4* yp = reinterpret_cast<const float4*>(y + ((size_t)n * L_ + t) * MIP_);
        const float4* wp = reinterpret_cast<const float4*>(((t < H_) ? w_h : w_w) + c * MIP_);
        float4 y0 = yp[0], y1 = yp[1];        // L2-hot (20K floats total)
        float4 w0 = wp[0], w1 = wp[1];        // uniform per half-block
        float s = y0.x * w0.x + y0.y * w0.y + y0.z * w0.z + y0.w * w0.w
                + y1.x * w1.x + y1.y * w1.y + y1.z * w1.z + y1.w * w1.w;
        float gate = 1.0f / (1.0f + expf(-s));
        if (t < H_) lah[t] = gate; else law[t - H_] = gate;
    }
    __syncthreads();

    const float4* xv = reinterpret_cast<const float4*>(x + (size_t)b * (H_ * W_));
    f32x4*        ov = reinterpret_cast<f32x4*>(out + (size_t)b * (H_ * W_));
    #pragma unroll
    for (int it = 0; it < 7; ++it) {
        int v = t + it * 256;
        if (v < 1600) {
            float4 q = xv[v];
            int row  = v / 20;
            int col0 = (v - row * 20) * 4;
            const float ah = lah[row];
            f32x4 o;
            o.x = q.x * ah * law[col0    ];
            o.y = q.y * ah * law[col0 + 1];
            o.z = q.z * ah * law[col0 + 2];
            o.w = q.w * ah * law[col0 + 3];
            __builtin_nontemporal_store(o, &ov[v]);   // out is write-once: don't evict x
        }
    }
}

extern "C" void kernel_launch(void* const* d_in, const int* in_sizes, int n_in,
                              void* d_out, int out_size, void* d_ws, size_t ws_size,
                              hipStream_t stream) {
    const float* x    = (const float*)d_in[0];
    const float* w_fc = (const float*)d_in[1];
    const float* g    = (const float*)d_in[2];
    const float* be   = (const float*)d_in[3];
    const float* mu   = (const float*)d_in[4];
    const float* va   = (const float*)d_in[5];
    const float* w_h  = (const float*)d_in[6];
    const float* w_w  = (const float*)d_in[7];
    float* out = (float*)d_out;

    float* pooled = (float*)d_ws;                        // N*C*L floats = 2.62 MB
    float* y      = pooled + (size_t)N_ * C_ * L_;       // N*L*MIP floats = 80 KB

    pool_kernel <<<N_ * C_, 256, 0, stream>>>(x, pooled);
    mid_kernel  <<<N_ * L_, 256, 0, stream>>>(pooled, w_fc, g, be, mu, va, y);
    apply_kernel<<<N_ * C_, 256, 0, stream>>>(x, y, w_h, w_w, out);
}

// Round 4
// 220.866 us; speedup vs baseline: 1.3010x; 1.0110x over previous
//
#include <hip/hip_runtime.h>

// LightCoordAtt: x (N,C,H,W) f32 in, f32 out. N=16, C=256, H=W=80, mip=8, L=160.
// Dtypes settled in prior session: f32 in, f32 out (bf16 paths failed absmax).
//
// R4 = R3 (223.3 us) with apply restructured to 4 planes/block; pool and mid
// byte-identical to R3 for a clean single-variable A/B.
// Journal: R1: cross-XCD atomicAdd fusion -> 84 MB write-back, +62 us (NEVER).
//          R3: NT stores on out -> -2 us (noise; kept, semantically right).
//          Apply theory now: per-block overhead + shallow pipelining, not cache
//          policy. 1024 blocks x 25 unconditional float4/thread, 640 gates and
//          one barrier per block instead of 4x160 gates + 4 barriers.
#define N_   16
#define C_   256
#define H_   80
#define W_   80
#define MIP_ 8
#define L_   160

typedef float f32x4 __attribute__((ext_vector_type(4)));   // native vector for NT store

// ---------------------------------------------------------------------------
// Kernel 1: per-(n,c) plane H-mean and W-mean. pooled layout: (n, c, l).
// ---------------------------------------------------------------------------
__global__ __launch_bounds__(256) void pool_kernel(const float* __restrict__ x,
                                                   float* __restrict__ pooled) {
    __shared__ float lds[H_ * 81];   // stride 81: odd stride -> conflict-free col reads
    const int b = blockIdx.x;        // n*C_ + c
    const int t = threadIdx.x;

    const float4* pv = reinterpret_cast<const float4*>(x + (size_t)b * (H_ * W_));
    #pragma unroll
    for (int it = 0; it < 7; ++it) {          // 1600 float4, 20 per row
        int v = t + it * 256;
        if (v < 1600) {
            float4 q = pv[v];
            int row  = v / 20;
            int col0 = (v - row * 20) * 4;
            float* dst = &lds[row * 81 + col0];
            dst[0] = q.x; dst[1] = q.y; dst[2] = q.z; dst[3] = q.w;
        }
    }
    __syncthreads();

    float* outp = pooled + (size_t)b * L_;
    if (t < H_) {                              // waves 0-1: row means -> x_h
        float s0 = 0.f, s1 = 0.f, s2 = 0.f, s3 = 0.f;
        const float* r = &lds[t * 81];
        #pragma unroll
        for (int c4 = 0; c4 < W_; c4 += 4) {
            s0 += r[c4]; s1 += r[c4 + 1]; s2 += r[c4 + 2]; s3 += r[c4 + 3];
        }
        outp[t] = (s0 + s1 + s2 + s3) * (1.0f / (float)W_);
    } else if (t >= 128 && t < 128 + W_) {     // waves 2-3: col means -> x_w
        const int j = t - 128;
        float s0 = 0.f, s1 = 0.f, s2 = 0.f, s3 = 0.f;
        #pragma unroll
        for (int r4 = 0; r4 < H_; r4 += 4) {
            s0 += lds[(r4    ) * 81 + j];
            s1 += lds[(r4 + 1) * 81 + j];
            s2 += lds[(r4 + 2) * 81 + j];
            s3 += lds[(r4 + 3) * 81 + j];
        }
        outp[H_ + j] = (s0 + s1 + s2 + s3) * (1.0f / (float)H_);
    }
}

// ---------------------------------------------------------------------------
// Kernel 2: y[n,l,m] = swish( BN( sum_c w_fc[m,c] * pooled[n,c,l] ) )
// ---------------------------------------------------------------------------
__global__ __launch_bounds__(256) void mid_kernel(const float* __restrict__ pooled,
                                                  const float* __restrict__ w_fc,
                                                  const float* __restrict__ g,
                                                  const float* __restrict__ be,
                                                  const float* __restrict__ mu,
                                                  const float* __restrict__ va,
                                                  float* __restrict__ y_out) {
    __shared__ float red[4 * MIP_];
    const int b    = blockIdx.x;          // n*L_ + l
    const int n    = b / L_;
    const int l    = b - n * L_;
    const int c    = threadIdx.x;
    const int lane = c & 63;
    const int wid  = c >> 6;

    // scattered 4B reads at 640B stride; pooled is 2.6 MB, L2/L3-hot
    const float p = pooled[((size_t)n * C_ + c) * L_ + l];

    #pragma unroll
    for (int m = 0; m < MIP_; ++m) {
        float v = w_fc[m * C_ + c] * p;
        #pragma unroll
        for (int off = 32; off > 0; off >>= 1) v += __shfl_down(v, off, 64);
        if (lane == 0) red[wid * MIP_ + m] = v;
    }
    __syncthreads();

    if (c < MIP_) {
        float y   = red[c] + red[MIP_ + c] + red[2 * MIP_ + c] + red[3 * MIP_ + c];
        float inv = g[c] * rsqrtf(va[c] + 1e-5f);
        y = y * inv + (be[c] - mu[c] * inv);
        y_out[(size_t)b * MIP_ + c] = y / (1.0f + expf(-y));   // swish
    }
}

// ---------------------------------------------------------------------------
// Kernel 3: 4 planes per block. Gates for channels c0..c0+3 inline, then
// out[n,c,h,w] = x * sigmoid(w_h[c].y_h[h]) * sigmoid(w_w[c].y_w[w])
// Stream phase: 6400 float4 = exactly 25 per thread, no bounds checks.
// ---------------------------------------------------------------------------
__global__ __launch_bounds__(256) void apply_kernel(const float* __restrict__ x,
                                                    const float* __restrict__ y,
                                                    const float* __restrict__ w_h,
                                                    const float* __restrict__ w_w,
                                                    float* __restrict__ out) {
    __shared__ float lah[4][H_];
    __shared__ float law[4][W_];
    const int b  = blockIdx.x;            // 0..1023
    const int n  = b >> 6;                // b / 64
    const int c0 = (b & 63) << 2;         // 4 * (b % 64)
    const int t  = threadIdx.x;

    // 640 gates: idx = t, 256+t, and 512+t for t<128. idx -> (ch, l).
    #pragma unroll
    for (int pass = 0; pass < 3; ++pass) {
        int idx = t + pass * 256;
        if (idx < 4 * L_) {
            int ch = idx / L_;
            int l  = idx - ch * L_;
            int c  = c0 + ch;
            const float4* yp = reinterpret_cast<const float4*>(y + ((size_t)n * L_ + l) * MIP_);
            const float4* wp = reinterpret_cast<const float4*>(((l < H_) ? w_h : w_w) + c * MIP_);
            float4 y0 = yp[0], y1 = yp[1];        // L2-hot (20K floats total)
            float4 w0 = wp[0], w1 = wp[1];
            float s = y0.x * w0.x + y0.y * w0.y + y0.z * w0.z + y0.w * w0.w
                    + y1.x * w1.x + y1.y * w1.y + y1.z * w1.z + y1.w * w1.w;
            float gate = 1.0f / (1.0f + expf(-s));
            if (l < H_) lah[ch][l] = gate; else law[ch][l - H_] = gate;
        }
    }
    __syncthreads();

    // Stream 4 contiguous planes: x + (n*256 + c0)*6400, 25600 floats.
    const float4* xv = reinterpret_cast<const float4*>(x + ((size_t)n * C_ + c0) * (H_ * W_));
    f32x4*        ov = reinterpret_cast<f32x4*>(out + ((size_t)n * C_ + c0) * (H_ * W_));
    #pragma unroll
    for (int it = 0; it < 25; ++it) {             // 6400 = 25 * 256 exactly
        int v     = t + it * 256;
        int plane = v / 1600;
        int vv    = v - plane * 1600;
        int row   = vv / 20;
        int col0  = (vv - row * 20) * 4;
        float4 q  = xv[v];
        const float ah = lah[plane][row];
        const float* lw = &law[plane][col0];
        f32x4 o;
        o.x = q.x * ah * lw[0];
        o.y = q.y * ah * lw[1];
        o.z = q.z * ah * lw[2];
        o.w = q.w * ah * lw[3];
        __builtin_nontemporal_store(o, &ov[v]);   // out is write-once
    }
}

extern "C" void kernel_launch(void* const* d_in, const int* in_sizes, int n_in,
                              void* d_out, int out_size, void* d_ws, size_t ws_size,
                              hipStream_t stream) {
    const float* x    = (const float*)d_in[0];
    const float* w_fc = (const float*)d_in[1];
    const float* g    = (const float*)d_in[2];
    const float* be   = (const float*)d_in[3];
    const float* mu   = (const float*)d_in[4];
    const float* va   = (const float*)d_in[5];
    const float* w_h  = (const float*)d_in[6];
    const float* w_w  = (const float*)d_in[7];
    float* out = (float*)d_out;

    float* pooled = (float*)d_ws;                        // N*C*L floats = 2.62 MB
    float* y      = pooled + (size_t)N_ * C_ * L_;       // N*L*MIP floats = 80 KB

    pool_kernel <<<N_ * C_,     256, 0, stream>>>(x, pooled);
    mid_kernel  <<<N_ * L_,     256, 0, stream>>>(pooled, w_fc, g, be, mu, va, y);
    apply_kernel<<<N_ * C_ / 4, 256, 0, stream>>>(x, y, w_h, w_w, out);
}